// Round 15
// baseline (187.560 us; speedup 1.0000x reference)
//
#include <hip/hip_runtime.h>

constexpr int Bn  = 4;
constexpr int Sn  = 1024;
constexpr int Dn  = 1024;
constexpr int Hn  = 16;
constexpr int HDn = 64;

using short8   = __attribute__((ext_vector_type(8))) short;
using float4v  = __attribute__((ext_vector_type(4))) float;
using float16v = __attribute__((ext_vector_type(16))) float;

__device__ __forceinline__ ushort f2bf(float f) {
    union { float f; unsigned u; } v; v.f = f;
    unsigned r = v.u + 0x7fff + ((v.u >> 16) & 1);   // RNE
    return (ushort)(r >> 16);
}

__device__ __forceinline__ void gload16(const void* g, void* l) {
    __builtin_amdgcn_global_load_lds(
        (const __attribute__((address_space(1))) void*)g,
        (__attribute__((address_space(3))) void*)l, 16, 0, 0);
}

// ---------------------------------------------------------------------------
// prep (R22-proven) — 2816 blocks, heavy first:
//   [0,768)     transpose_w: W (KxN fp32) -> Wt (NxK bf16), 64x64 LDS tiles
//   [768,2816)  convert_x: x fp32 -> xb bf16
// ---------------------------------------------------------------------------
__global__ __launch_bounds__(256) void prep(
    const float* __restrict__ x,
    const float* __restrict__ Wq, const float* __restrict__ Wk,
    const float* __restrict__ Wv,
    ushort* __restrict__ xb, ushort* __restrict__ Wt)
{
    const int bx  = blockIdx.x;
    const int tid = threadIdx.x;
    __shared__ __align__(16) ushort pool[64 * 72];   // 9216 B

    if (bx < 768) {
        // ---- transpose_w ----
        const int idx = bx;
        const int which = idx >> 8, rem = idx & 255;
        const float* __restrict__ W = (which == 0) ? Wq : (which == 1) ? Wk : Wv;
        ushort* __restrict__ O = Wt + (size_t)which * Dn * Dn;
        const int k0 = (rem & 15) * 64, n0 = (rem >> 4) * 64;
        ushort* T = pool;

        const int kl = tid >> 4, nl = (tid & 15) * 4;
#pragma unroll
        for (int p = 0; p < 4; ++p) {
            float4 w4 = *(const float4*)&W[(size_t)(k0 + p * 16 + kl) * Dn + n0 + nl];
            T[(nl + 0) * 72 + p * 16 + kl] = f2bf(w4.x);
            T[(nl + 1) * 72 + p * 16 + kl] = f2bf(w4.y);
            T[(nl + 2) * 72 + p * 16 + kl] = f2bf(w4.z);
            T[(nl + 3) * 72 + p * 16 + kl] = f2bf(w4.w);
        }
        __syncthreads();
        const int nr = tid >> 2, kc = (tid & 3) * 16;
        uint4 u0 = *(const uint4*)&T[nr * 72 + kc];
        uint4 u1 = *(const uint4*)&T[nr * 72 + kc + 8];
        *(uint4*)&O[(size_t)(n0 + nr) * Dn + k0 + kc]     = u0;
        *(uint4*)&O[(size_t)(n0 + nr) * Dn + k0 + kc + 8] = u1;
    } else {
        // ---- convert_x ----
        const size_t i = ((size_t)(bx - 768) * 256 + tid) * 8;
        float4 a = *(const float4*)&x[i];
        float4 b = *(const float4*)&x[i + 4];
        ushort o[8] = {f2bf(a.x), f2bf(a.y), f2bf(a.z), f2bf(a.w),
                       f2bf(b.x), f2bf(b.y), f2bf(b.z), f2bf(b.w)};
        *(uint4*)&xb[i] = *(const uint4*)o;
    }
}

// ---------------------------------------------------------------------------
// qkv_gemm + mask (R25: GEMM blocks FIRST): grid 1280 = 768 GEMM (bx<768,
// n=bx preserves n&7 XCD decode) + 512 mask (bx>=768). All 768 GEMM blocks
// resident at t=0 (3/CU from 32KB LDS, 4-block capacity leaves slot 4 for
// masks); masks run on the HBM pipe GEMM leaves 90% idle. R14 (mask-first)
// proved full overlap: fused = 45 µs ≈ standalone GEMM.
// GEMM: R4-proven 2-buffer single-barrier loop. Ledger CLOSED: 2-bar 43.4 |
// dbuf-1 45.0 | 3-buf 43.0 | B-direct 92 | 256² 61.8 | forced-occ 230 (R13:
// NEVER __launch_bounds__ min-waves on register-heavy MFMA — spilled acc).
// Mask pack: INTEGER byte-pack (exact). Mask layout (proven):
// dst = Mb + ((((b*8+qt)*16+kt)*4+w)*64+lane)*16.
// ---------------------------------------------------------------------------
__global__ __launch_bounds__(256) void qkv_gemm(
    const ushort* __restrict__ xb, const ushort* __restrict__ Wt,
    const float* __restrict__ bq, const float* __restrict__ bk,
    const float* __restrict__ bv, const float* __restrict__ adj,
    ushort* __restrict__ Qb, ushort* __restrict__ Kb, ushort* __restrict__ Vb,
    uint* __restrict__ Mb, float* __restrict__ out)
{
    const int tid = threadIdx.x;
    __shared__ __align__(16) ushort As[2][128 * 32];   // 16 KB
    __shared__ __align__(16) ushort Bs[2][128 * 32];   // 16 KB

    if (blockIdx.x >= 768) {
        // ================= mask + adj->out copy =================
        const int idx = blockIdx.x - 768;          // 0..511
        const int kt = idx & 15, qt = (idx >> 4) & 7, b = idx >> 7;
        char* msk = (char*)&As[0][0];              // [128][68], 8704 B <= 32K

        float* ocopy = out + (size_t)Bn * Sn * Dn;
        const int r16 = tid >> 4, c4 = (tid & 15) * 4;
#pragma unroll
        for (int p = 0; p < 8; ++p) {
            const int row = p * 16 + r16;
            const size_t gi = ((size_t)b * Sn + qt * 128 + row) * Sn + kt * 64 + c4;
            float4 a = *(const float4*)&adj[gi];
            *(float4*)&ocopy[gi] = a;
            // adj in {0.0,1.0} exactly -> integer byte-pack (exact)
            const uint pk = (uint)a.x | ((uint)a.y << 8) |
                            ((uint)a.z << 16) | ((uint)a.w << 24);
            *(uint*)&msk[row * 68 + c4] = pk;
        }
        __syncthreads();

        const int lane = tid & 63, w = tid >> 6;
        const int col = lane & 31, hi = lane >> 5;
        const char* mr = &msk[(w * 32 + col) * 68];
        uint words[16];
#pragma unroll
        for (int mt = 0; mt < 2; ++mt)
#pragma unroll
            for (int pr = 0; pr < 8; ++pr) {
                const int r0 = 2 * pr;
                const int kl = mt * 32 + (r0 & 3) + 8 * (r0 >> 2) + 4 * hi; // even
                const uint m2 = *(const ushort*)&mr[kl];   // bytes {0,1}
                words[mt * 8 + pr] = ((m2 & 1u) | ((m2 & 0x100u) << 8)) * 0xFFFFu;
            }
        uint* dst = Mb + ((((size_t)(b * 8 + qt) * 16 + kt) * 4 + w) * 64 + lane) * 16;
#pragma unroll
        for (int c = 0; c < 4; ++c)
            *(uint4*)&dst[c * 4] =
                make_uint4(words[c*4], words[c*4+1], words[c*4+2], words[c*4+3]);
        return;
    }

    // ================= GEMM (R4 2-buffer structure) =================
    const int n  = blockIdx.x;                // 0..767 (XCD decode on n&7)
    const int v  = (n & 7) * 96 + (n >> 3);
    const int by = v / 24;                    // 0..31
    const int rr = v - by * 24;
    const int bxi   = rr & 7;                 // 0..7
    const int which = rr >> 3;                // 0..2

    const ushort* __restrict__ Bw   = Wt + (size_t)which * Dn * Dn;
    const float* __restrict__  bias = (which == 0) ? bq : (which == 1) ? bk : bv;
    ushort* __restrict__       Out  = (which == 0) ? Qb : (which == 1) ? Kb : Vb;
    const float scale = (which == 0) ? 0.18033688011112042f : 1.0f;  // 0.125*log2(e)

    const int n0   = bxi * 128;
    const int m0   = by * 128;
    const int wave = tid >> 6;
    const int lane = tid & 63;
    const int wm   = wave >> 1;
    const int wn   = wave & 1;

    const int L0 = wave * 64 + lane;
    const int r0s = L0 >> 2, c0s = ((L0 & 3) ^ ((L0 >> 3) & 3)) * 8;  // swizzled src chunk
    const int L1 = L0 + 256;
    const int r1s = L1 >> 2, c1s = ((L1 & 3) ^ ((L1 >> 3) & 3)) * 8;

    const ushort* pA0 = &xb[(size_t)(m0 + r0s) * Dn + c0s];
    const ushort* pA1 = &xb[(size_t)(m0 + r1s) * Dn + c1s];
    const ushort* pB0 = &Bw[(size_t)(n0 + r0s) * Dn + c0s];
    const ushort* pB1 = &Bw[(size_t)(n0 + r1s) * Dn + c1s];

    char* ldsA0b = (char*)As + wave * 1024;
    char* ldsA1b = (char*)As + wave * 1024 + 4096;
    char* ldsB0b = (char*)Bs + wave * 1024;
    char* ldsB1b = (char*)Bs + wave * 1024 + 4096;

    const int mlane = lane & 15;
    const int kg = (((lane >> 4) ^ ((mlane >> 1) & 3))) * 8;

    float4v acc[4][4];
    const float4v z4 = {0.f, 0.f, 0.f, 0.f};
#pragma unroll
    for (int i = 0; i < 4; ++i)
#pragma unroll
        for (int j = 0; j < 4; ++j) acc[i][j] = z4;

    // prologue: stage K-tile 0 into buf 0
    gload16(pA0, ldsA0b);
    gload16(pA1, ldsA1b);
    gload16(pB0, ldsB0b);
    gload16(pB1, ldsB1b);
    pA0 += 32; pA1 += 32; pB0 += 32; pB1 += 32;
    __syncthreads();   // implicit vmcnt(0): tile 0 landed

    for (int k0 = 0; k0 < Dn; k0 += 32) {
        const int cur = (k0 >> 5) & 1;
        const int nxt = cur ^ 1;
        if (k0 + 32 < Dn) {
            // stage tile k+1 into the other buffer; overlaps with MFMA below
            gload16(pA0, ldsA0b + nxt * 8192);
            gload16(pA1, ldsA1b + nxt * 8192);
            gload16(pB0, ldsB0b + nxt * 8192);
            gload16(pB1, ldsB1b + nxt * 8192);
            pA0 += 32; pA1 += 32; pB0 += 32; pB1 += 32;
        }

        short8 af[4], bf[4];
#pragma unroll
        for (int i = 0; i < 4; ++i)
            af[i] = *(const short8*)&As[cur][(wm * 64 + i * 16 + mlane) * 32 + kg];
#pragma unroll
        for (int j = 0; j < 4; ++j)
            bf[j] = *(const short8*)&Bs[cur][(wn * 64 + j * 16 + mlane) * 32 + kg];
        __builtin_amdgcn_s_setprio(1);
#pragma unroll
        for (int i = 0; i < 4; ++i)
#pragma unroll
            for (int j = 0; j < 4; ++j)
                acc[i][j] = __builtin_amdgcn_mfma_f32_16x16x32_bf16(af[i], bf[j], acc[i][j], 0, 0, 0);
        __builtin_amdgcn_s_setprio(0);

        __syncthreads();   // one barrier/K-step: drains prefetch + all reads
    }

    const int rb  = (lane >> 4) * 4;
    const int col = lane & 15;
#pragma unroll
    for (int j = 0; j < 4; ++j) {
        const int nn = n0 + wn * 64 + j * 16 + col;
        const float bias_n = bias[nn];
        const int h  = nn >> 6;
        const int hd = nn & 63;
#pragma unroll
        for (int i = 0; i < 4; ++i) {
            const int m = m0 + wm * 64 + i * 16 + rb;
            const int b = m >> 10;
            const int s = m & 1023;
            if (which == 2) {
                // V transposed: r = consecutive s -> one 8-B store (scale==1)
                ushort4 v4;
                v4.x = f2bf(acc[i][j][0] + bias_n);
                v4.y = f2bf(acc[i][j][1] + bias_n);
                v4.z = f2bf(acc[i][j][2] + bias_n);
                v4.w = f2bf(acc[i][j][3] + bias_n);
                *(ushort4*)&Out[(((size_t)(b * Hn + h)) * HDn + hd) * Sn + s] = v4;
            } else {
#pragma unroll
                for (int r = 0; r < 4; ++r) {
                    const size_t addr = (((size_t)(b * Hn + h)) * Sn + (s + r)) * HDn + hd;
                    Out[addr] = f2bf((acc[i][j][r] + bias_n) * scale);
                }
            }
        }
    }
}

// ---------------------------------------------------------------------------
// MFMA flash attention, split-K over keys + R25 QK-hoist (T15 analog):
// per kt, BOTH mt-halves' QK^T accumulators (s0,s1) are computed first
// (8-MFMA cluster), then softmax+PV per half. QK(mt1)'s MFMA latency hides
// under softmax(mt0)'s VALU chain — the two halves are independent until
// PV-accumulate, and PV order (mt0 then mt1) is preserved exactly.
// Occupancy is GRID-limited (512 blocks = 2/CU), so the +16 VGPR for the
// second accumulator is free headroom (bounds allow 128; was 64).
// Mask loaded at top of each kt (R2's explicit prefetch spilled; don't).
// Pack via v_permlane32_swap_b32; s_setprio(1) around MFMA clusters (T5).
// Cross-group combine via one LDS exchange (exp2 softmax -> pure (o,l) add).
// XCD swizzle: co-(b,h) blocks share an XCD L2.
// ---------------------------------------------------------------------------
__global__ __launch_bounds__(512, 4) void attn_mfma(
    const ushort* __restrict__ Q, const ushort* __restrict__ K,
    const ushort* __restrict__ Vt, const uint* __restrict__ Mw,
    float* __restrict__ out)
{
    const int n  = blockIdx.x;                 // 0..511
    const int qt = (n >> 3) & 7;
    const int bh = (n & 7) | ((n >> 6) << 3);  // 0..63
    const int h  = bh & 15;
    const int b  = bh >> 4;

    const int tid  = threadIdx.x;
    const int w    = tid >> 6, lane = tid & 63;
    const int g    = w >> 2;                   // key-half group
    const int wq   = w & 3;                    // q-subtile within block
    const int col  = lane & 31, hi = lane >> 5;

    const size_t hb = ((size_t)(b * Hn + h)) * Sn * HDn;
    const ushort* Kg = K + hb;          // [key][dim]
    const ushort* Vg = Vt + hb;         // [dim][key]

    __shared__ __align__(16) ushort KV[2][2][2][64 * 72];

    short8 qf[4];
#pragma unroll
    for (int kp = 0; kp < 4; ++kp)
        qf[kp] = *(const short8*)&Q[hb +
            (size_t)(qt * 128 + wq * 32 + col) * HDn + kp * 16 + hi * 8];

    float16v o_[2];
#pragma unroll
    for (int dt = 0; dt < 2; ++dt)
#pragma unroll
        for (int r = 0; r < 16; ++r) o_[dt][r] = 0.f;
    float ls = 0.f;

    const int t  = tid & 255;
    const int c0 = t, c1 = t + 256;
    const int la0 = (c0 >> 3) * 72 + (c0 & 7) * 8;
    const int la1 = (c1 >> 3) * 72 + (c1 & 7) * 8;
    const int kb  = g * 8;                     // first key-tile of this group

    uint4 k0 = *(const uint4*)&Kg[(size_t)(kb * 64 + (c0 >> 3)) * HDn + (c0 & 7) * 8];
    uint4 k1 = *(const uint4*)&Kg[(size_t)(kb * 64 + (c1 >> 3)) * HDn + (c1 & 7) * 8];
    uint4 v0 = *(const uint4*)&Vg[(size_t)(c0 >> 3) * Sn + kb * 64 + (c0 & 7) * 8];
    uint4 v1 = *(const uint4*)&Vg[(size_t)(c1 >> 3) * Sn + kb * 64 + (c1 & 7) * 8];
    *(uint4*)&KV[g][0][0][la0] = k0;  *(uint4*)&KV[g][0][0][la1] = k1;
    *(uint4*)&KV[g][0][1][la0] = v0;  *(uint4*)&KV[g][0][1][la1] = v1;
    __syncthreads();

    const uint* mbase = Mw + ((size_t)((b * 8 + qt) * 16) * 4 + wq) * 1024 + lane * 16;

    for (int kt = 0; kt < 8; ++kt) {
        const int cur = kt & 1;
        if (kt < 7) {
            const int nk = (kb + kt + 1) * 64;
            k0 = *(const uint4*)&Kg[(size_t)(nk + (c0 >> 3)) * HDn + (c0 & 7) * 8];
            k1 = *(const uint4*)&Kg[(size_t)(nk + (c1 >> 3)) * HDn + (c1 & 7) * 8];
            v0 = *(const uint4*)&Vg[(size_t)(c0 >> 3) * Sn + nk + (c0 & 7) * 8];
            v1 = *(const uint4*)&Vg[(size_t)(c1 >> 3) * Sn + nk + (c1 & 7) * 8];
        }
        const uint* mp = mbase + (size_t)(kb + kt) * 4096;
        uint4 mk4[4];
        mk4[0] = *(const uint4*)(mp);
        mk4[1] = *(const uint4*)(mp + 4);
        mk4[2] = *(const uint4*)(mp + 8);
        mk4[3] = *(const uint4*)(mp + 12);
        const uint* mka = (const uint*)mk4;   // [mt*8 + pr]

        // ---- QK^T for BOTH mt halves up front (R25: hide QK1 under SM0) ----
        float16v sm[2];
#pragma unroll
        for (int r = 0; r < 16; ++r) { sm[0][r] = 0.f; sm[1][r] = 0.f; }
        __builtin_amdgcn_s_setprio(1);
#pragma unroll
        for (int mt = 0; mt < 2; ++mt)
#pragma unroll
            for (int kp = 0; kp < 4; ++kp) {
                short8 ak = *(const short8*)&KV[g][cur][0][(mt * 32 + col) * 72 + kp * 16 + hi * 8];
                sm[mt] = __builtin_amdgcn_mfma_f32_32x32x16_bf16(ak, qf[kp], sm[mt], 0, 0, 0);
            }
        __builtin_amdgcn_s_setprio(0);

#pragma unroll
        for (int mt = 0; mt < 2; ++mt) {
            unsigned up[8];
#pragma unroll
            for (int pr = 0; pr < 8; ++pr) {
                const unsigned e0 = __float_as_uint(exp2f(sm[mt][2 * pr]))     + 0x8000u;
                const unsigned e1 = __float_as_uint(exp2f(sm[mt][2 * pr + 1])) + 0x8000u;
                const unsigned u  = __builtin_amdgcn_perm(e1, e0, 0x07060302u) & mka[mt * 8 + pr];
                up[pr] = u;
                ls += __uint_as_float(u << 16) + __uint_as_float(u & 0xffff0000u);
            }

            __builtin_amdgcn_s_setprio(1);
#pragma unroll
            for (int kh = 0; kh < 2; ++kh) {
                auto s02 = __builtin_amdgcn_permlane32_swap(
                    up[kh * 4 + 0], up[kh * 4 + 2], false, false);
                auto s13 = __builtin_amdgcn_permlane32_swap(
                    up[kh * 4 + 1], up[kh * 4 + 3], false, false);
                union { short8 s; unsigned u[4]; } f;
                f.u[0] = s02[0];
                f.u[1] = s13[0];
                f.u[2] = s02[1];
                f.u[3] = s13[1];
                const int kp = mt * 2 + kh;
#pragma unroll
                for (int dt = 0; dt < 2; ++dt) {
                    short8 av = *(const short8*)&KV[g][cur][1][(dt * 32 + col) * 72 + kp * 16 + hi * 8];
                    o_[dt] = __builtin_amdgcn_mfma_f32_32x32x16_bf16(av, f.s, o_[dt], 0, 0, 0);
                }
            }
            __builtin_amdgcn_s_setprio(0);
        }

        if (kt < 7) {
            const int nxt = cur ^ 1;
            *(uint4*)&KV[g][nxt][0][la0] = k0;  *(uint4*)&KV[g][nxt][0][la1] = k1;
            *(uint4*)&KV[g][nxt][1][la0] = v0;  *(uint4*)&KV[g][nxt][1][la1] = v1;
        }
        __syncthreads();
    }

    // ---- cross-group combine (reuse KV LDS; all tile reads done) ----
    float* xo  = (float*)&KV[0][0][0][0];         // 4 waves x 64 lanes x 36 f32
    float* lsx = xo + 4 * 64 * 36;                // + 256 f32  (38.9 KB total)
    if (g == 1) {
        float* dst = &xo[(wq * 64 + lane) * 36];
#pragma unroll
        for (int dt = 0; dt < 2; ++dt)
#pragma unroll
            for (int r4 = 0; r4 < 4; ++r4) {
                float4 o4 = make_float4(o_[dt][r4 * 4 + 0], o_[dt][r4 * 4 + 1],
                                        o_[dt][r4 * 4 + 2], o_[dt][r4 * 4 + 3]);
                *(float4*)&dst[dt * 16 + r4 * 4] = o4;
            }
        lsx[wq * 64 + lane] = ls;
    }
    __syncthreads();
    if (g == 0) {
        const float* src = &xo[(wq * 64 + lane) * 36];
        const float lt = ls + lsx[wq * 64 + lane];
        const float l  = lt + (float)__shfl_xor(lt, 32, 64);
        const float inv = 1.0f / l;
        const int q = qt * 128 + wq * 32 + col;
        float* op = &out[((size_t)b * Sn + q) * Dn + h * 64];
#pragma unroll
        for (int dt = 0; dt < 2; ++dt)
#pragma unroll
            for (int rg = 0; rg < 4; ++rg) {
                float4 s4 = *(const float4*)&src[dt * 16 + rg * 4];
                const int d = dt * 32 + rg * 8 + hi * 4;
                float4 o4;
                o4.x = fmaxf((o_[dt][rg * 4 + 0] + s4.x) * inv, 0.0f);
                o4.y = fmaxf((o_[dt][rg * 4 + 1] + s4.y) * inv, 0.0f);
                o4.z = fmaxf((o_[dt][rg * 4 + 2] + s4.z) * inv, 0.0f);
                o4.w = fmaxf((o_[dt][rg * 4 + 3] + s4.w) * inv, 0.0f);
                *(float4*)&op[d] = o4;
            }
    }
}

extern "C" void kernel_launch(void* const* d_in, const int* in_sizes, int n_in,
                              void* d_out, int out_size, void* d_ws, size_t ws_size,
                              hipStream_t stream)
{
    const float* x   = (const float*)d_in[0];
    const float* adj = (const float*)d_in[1];
    const float* Wq  = (const float*)d_in[2];
    const float* bq  = (const float*)d_in[3];
    const float* Wk  = (const float*)d_in[4];
    const float* bk  = (const float*)d_in[5];
    const float* Wv  = (const float*)d_in[6];
    const float* bv  = (const float*)d_in[7];
    float* out = (float*)d_out;

    // ws (ushort): xb[4.19M] | Wt[3.15M] | Qb | Kb | Vb [4.19M ea] then Mb (uint, 8.4 MB)
    ushort* xb = (ushort*)d_ws;
    ushort* Wt = xb + (size_t)Bn * Sn * Dn;
    ushort* Qb = Wt + (size_t)3 * Dn * Dn;
    ushort* Kb = Qb + (size_t)Bn * Hn * Sn * HDn;
    ushort* Vb = Kb + (size_t)Bn * Hn * Sn * HDn;
    uint*   Mb = (uint*)(Vb + (size_t)Bn * Hn * Sn * HDn);

    prep<<<dim3(2816), 256, 0, stream>>>(x, Wq, Wk, Wv, xb, Wt);

    qkv_gemm<<<dim3(1280), 256, 0, stream>>>(
        xb, Wt, bq, bk, bv, adj, Qb, Kb, Vb, Mb, out);

    attn_mfma<<<dim3(512), 512, 0, stream>>>(Qb, Kb, Vb, Mb, out);
}

// Round 16
// 170.646 us; speedup vs baseline: 1.0991x; 1.0991x over previous
//
#include <hip/hip_runtime.h>

constexpr int Bn  = 4;
constexpr int Sn  = 1024;
constexpr int Dn  = 1024;
constexpr int Hn  = 16;
constexpr int HDn = 64;

using short8   = __attribute__((ext_vector_type(8))) short;
using float4v  = __attribute__((ext_vector_type(4))) float;
using float16v = __attribute__((ext_vector_type(16))) float;

__device__ __forceinline__ ushort f2bf(float f) {
    union { float f; unsigned u; } v; v.f = f;
    unsigned r = v.u + 0x7fff + ((v.u >> 16) & 1);   // RNE
    return (ushort)(r >> 16);
}

__device__ __forceinline__ void gload16(const void* g, void* l) {
    __builtin_amdgcn_global_load_lds(
        (const __attribute__((address_space(1))) void*)g,
        (__attribute__((address_space(3))) void*)l, 16, 0, 0);
}

// ---------------------------------------------------------------------------
// prep (R22-proven) — 2816 blocks, heavy first:
//   [0,768)     transpose_w: W (KxN fp32) -> Wt (NxK bf16), 64x64 LDS tiles
//   [768,2816)  convert_x: x fp32 -> xb bf16
// ---------------------------------------------------------------------------
__global__ __launch_bounds__(256) void prep(
    const float* __restrict__ x,
    const float* __restrict__ Wq, const float* __restrict__ Wk,
    const float* __restrict__ Wv,
    ushort* __restrict__ xb, ushort* __restrict__ Wt)
{
    const int bx  = blockIdx.x;
    const int tid = threadIdx.x;
    __shared__ __align__(16) ushort pool[64 * 72];   // 9216 B

    if (bx < 768) {
        // ---- transpose_w ----
        const int idx = bx;
        const int which = idx >> 8, rem = idx & 255;
        const float* __restrict__ W = (which == 0) ? Wq : (which == 1) ? Wk : Wv;
        ushort* __restrict__ O = Wt + (size_t)which * Dn * Dn;
        const int k0 = (rem & 15) * 64, n0 = (rem >> 4) * 64;
        ushort* T = pool;

        const int kl = tid >> 4, nl = (tid & 15) * 4;
#pragma unroll
        for (int p = 0; p < 4; ++p) {
            float4 w4 = *(const float4*)&W[(size_t)(k0 + p * 16 + kl) * Dn + n0 + nl];
            T[(nl + 0) * 72 + p * 16 + kl] = f2bf(w4.x);
            T[(nl + 1) * 72 + p * 16 + kl] = f2bf(w4.y);
            T[(nl + 2) * 72 + p * 16 + kl] = f2bf(w4.z);
            T[(nl + 3) * 72 + p * 16 + kl] = f2bf(w4.w);
        }
        __syncthreads();
        const int nr = tid >> 2, kc = (tid & 3) * 16;
        uint4 u0 = *(const uint4*)&T[nr * 72 + kc];
        uint4 u1 = *(const uint4*)&T[nr * 72 + kc + 8];
        *(uint4*)&O[(size_t)(n0 + nr) * Dn + k0 + kc]     = u0;
        *(uint4*)&O[(size_t)(n0 + nr) * Dn + k0 + kc + 8] = u1;
    } else {
        // ---- convert_x ----
        const size_t i = ((size_t)(bx - 768) * 256 + tid) * 8;
        float4 a = *(const float4*)&x[i];
        float4 b = *(const float4*)&x[i + 4];
        ushort o[8] = {f2bf(a.x), f2bf(a.y), f2bf(a.z), f2bf(a.w),
                       f2bf(b.x), f2bf(b.y), f2bf(b.z), f2bf(b.w)};
        *(uint4*)&xb[i] = *(const uint4*)o;
    }
}

// ---------------------------------------------------------------------------
// qkv_gemm + mask (R24/R14-proven, FINAL): grid 1280 = 512 mask (bx<512)
// + 768 GEMM (bx-512; 512%8==0 preserves XCD decode). LDS 32 KB -> 4
// blocks/CU -> 1024 of 1280 resident at t=0; mask work (pure HBM) fully
// hides under GEMM (measured: fused 44.9-45.1 µs ≈ standalone GEMM 45.0).
// GEMM: R4-proven 2-buffer single-barrier loop. Ledger CLOSED: 2-bar 43.4 |
// dbuf-1 45.0 | 3-buf 43.0 | B-direct 92 | 256² 61.8 | forced-occ 230 (R13:
// NEVER __launch_bounds__ min-waves on register-heavy MFMA — spilled acc).
// Mask pack: INTEGER byte-pack (exact; float pack lost bits at 2^24+1).
// Mask layout (proven): dst = Mb + ((((b*8+qt)*16+kt)*4+w)*64+lane)*16.
// ---------------------------------------------------------------------------
__global__ __launch_bounds__(256) void qkv_gemm(
    const ushort* __restrict__ xb, const ushort* __restrict__ Wt,
    const float* __restrict__ bq, const float* __restrict__ bk,
    const float* __restrict__ bv, const float* __restrict__ adj,
    ushort* __restrict__ Qb, ushort* __restrict__ Kb, ushort* __restrict__ Vb,
    uint* __restrict__ Mb, float* __restrict__ out)
{
    const int tid = threadIdx.x;
    __shared__ __align__(16) ushort As[2][128 * 32];   // 16 KB
    __shared__ __align__(16) ushort Bs[2][128 * 32];   // 16 KB

    if (blockIdx.x < 512) {
        // ================= mask + adj->out copy =================
        const int idx = blockIdx.x;                // 0..511
        const int kt = idx & 15, qt = (idx >> 4) & 7, b = idx >> 7;
        char* msk = (char*)&As[0][0];              // [128][68], 8704 B <= 32K

        float* ocopy = out + (size_t)Bn * Sn * Dn;
        const int r16 = tid >> 4, c4 = (tid & 15) * 4;
#pragma unroll
        for (int p = 0; p < 8; ++p) {
            const int row = p * 16 + r16;
            const size_t gi = ((size_t)b * Sn + qt * 128 + row) * Sn + kt * 64 + c4;
            float4 a = *(const float4*)&adj[gi];
            *(float4*)&ocopy[gi] = a;
            // adj in {0.0,1.0} exactly -> integer byte-pack (exact)
            const uint pk = (uint)a.x | ((uint)a.y << 8) |
                            ((uint)a.z << 16) | ((uint)a.w << 24);
            *(uint*)&msk[row * 68 + c4] = pk;
        }
        __syncthreads();

        const int lane = tid & 63, w = tid >> 6;
        const int col = lane & 31, hi = lane >> 5;
        const char* mr = &msk[(w * 32 + col) * 68];
        uint words[16];
#pragma unroll
        for (int mt = 0; mt < 2; ++mt)
#pragma unroll
            for (int pr = 0; pr < 8; ++pr) {
                const int r0 = 2 * pr;
                const int kl = mt * 32 + (r0 & 3) + 8 * (r0 >> 2) + 4 * hi; // even
                const uint m2 = *(const ushort*)&mr[kl];   // bytes {0,1}
                words[mt * 8 + pr] = ((m2 & 1u) | ((m2 & 0x100u) << 8)) * 0xFFFFu;
            }
        uint* dst = Mb + ((((size_t)(b * 8 + qt) * 16 + kt) * 4 + w) * 64 + lane) * 16;
#pragma unroll
        for (int c = 0; c < 4; ++c)
            *(uint4*)&dst[c * 4] =
                make_uint4(words[c*4], words[c*4+1], words[c*4+2], words[c*4+3]);
        return;
    }

    // ================= GEMM (R4 2-buffer structure) =================
    const int n  = blockIdx.x - 512;          // 0..767 (512%8==0: XCD decode kept)
    const int v  = (n & 7) * 96 + (n >> 3);
    const int by = v / 24;                    // 0..31
    const int rr = v - by * 24;
    const int bxi   = rr & 7;                 // 0..7
    const int which = rr >> 3;                // 0..2

    const ushort* __restrict__ Bw   = Wt + (size_t)which * Dn * Dn;
    const float* __restrict__  bias = (which == 0) ? bq : (which == 1) ? bk : bv;
    ushort* __restrict__       Out  = (which == 0) ? Qb : (which == 1) ? Kb : Vb;
    const float scale = (which == 0) ? 0.18033688011112042f : 1.0f;  // 0.125*log2(e)

    const int n0   = bxi * 128;
    const int m0   = by * 128;
    const int wave = tid >> 6;
    const int lane = tid & 63;
    const int wm   = wave >> 1;
    const int wn   = wave & 1;

    const int L0 = wave * 64 + lane;
    const int r0s = L0 >> 2, c0s = ((L0 & 3) ^ ((L0 >> 3) & 3)) * 8;  // swizzled src chunk
    const int L1 = L0 + 256;
    const int r1s = L1 >> 2, c1s = ((L1 & 3) ^ ((L1 >> 3) & 3)) * 8;

    const ushort* pA0 = &xb[(size_t)(m0 + r0s) * Dn + c0s];
    const ushort* pA1 = &xb[(size_t)(m0 + r1s) * Dn + c1s];
    const ushort* pB0 = &Bw[(size_t)(n0 + r0s) * Dn + c0s];
    const ushort* pB1 = &Bw[(size_t)(n0 + r1s) * Dn + c1s];

    char* ldsA0b = (char*)As + wave * 1024;
    char* ldsA1b = (char*)As + wave * 1024 + 4096;
    char* ldsB0b = (char*)Bs + wave * 1024;
    char* ldsB1b = (char*)Bs + wave * 1024 + 4096;

    const int mlane = lane & 15;
    const int kg = (((lane >> 4) ^ ((mlane >> 1) & 3))) * 8;

    float4v acc[4][4];
    const float4v z4 = {0.f, 0.f, 0.f, 0.f};
#pragma unroll
    for (int i = 0; i < 4; ++i)
#pragma unroll
        for (int j = 0; j < 4; ++j) acc[i][j] = z4;

    // prologue: stage K-tile 0 into buf 0
    gload16(pA0, ldsA0b);
    gload16(pA1, ldsA1b);
    gload16(pB0, ldsB0b);
    gload16(pB1, ldsB1b);
    pA0 += 32; pA1 += 32; pB0 += 32; pB1 += 32;
    __syncthreads();   // implicit vmcnt(0): tile 0 landed

    for (int k0 = 0; k0 < Dn; k0 += 32) {
        const int cur = (k0 >> 5) & 1;
        const int nxt = cur ^ 1;
        if (k0 + 32 < Dn) {
            // stage tile k+1 into the other buffer; overlaps with MFMA below
            gload16(pA0, ldsA0b + nxt * 8192);
            gload16(pA1, ldsA1b + nxt * 8192);
            gload16(pB0, ldsB0b + nxt * 8192);
            gload16(pB1, ldsB1b + nxt * 8192);
            pA0 += 32; pA1 += 32; pB0 += 32; pB1 += 32;
        }

        short8 af[4], bf[4];
#pragma unroll
        for (int i = 0; i < 4; ++i)
            af[i] = *(const short8*)&As[cur][(wm * 64 + i * 16 + mlane) * 32 + kg];
#pragma unroll
        for (int j = 0; j < 4; ++j)
            bf[j] = *(const short8*)&Bs[cur][(wn * 64 + j * 16 + mlane) * 32 + kg];
        __builtin_amdgcn_s_setprio(1);
#pragma unroll
        for (int i = 0; i < 4; ++i)
#pragma unroll
            for (int j = 0; j < 4; ++j)
                acc[i][j] = __builtin_amdgcn_mfma_f32_16x16x32_bf16(af[i], bf[j], acc[i][j], 0, 0, 0);
        __builtin_amdgcn_s_setprio(0);

        __syncthreads();   // one barrier/K-step: drains prefetch + all reads
    }

    const int rb  = (lane >> 4) * 4;
    const int col = lane & 15;
#pragma unroll
    for (int j = 0; j < 4; ++j) {
        const int nn = n0 + wn * 64 + j * 16 + col;
        const float bias_n = bias[nn];
        const int h  = nn >> 6;
        const int hd = nn & 63;
#pragma unroll
        for (int i = 0; i < 4; ++i) {
            const int m = m0 + wm * 64 + i * 16 + rb;
            const int b = m >> 10;
            const int s = m & 1023;
            if (which == 2) {
                // V transposed: r = consecutive s -> one 8-B store (scale==1)
                ushort4 v4;
                v4.x = f2bf(acc[i][j][0] + bias_n);
                v4.y = f2bf(acc[i][j][1] + bias_n);
                v4.z = f2bf(acc[i][j][2] + bias_n);
                v4.w = f2bf(acc[i][j][3] + bias_n);
                *(ushort4*)&Out[(((size_t)(b * Hn + h)) * HDn + hd) * Sn + s] = v4;
            } else {
#pragma unroll
                for (int r = 0; r < 4; ++r) {
                    const size_t addr = (((size_t)(b * Hn + h)) * Sn + (s + r)) * HDn + hd;
                    Out[addr] = f2bf((acc[i][j][r] + bias_n) * scale);
                }
            }
        }
    }
}

// ---------------------------------------------------------------------------
// MFMA flash attention, split-K over keys (R8-proven, FINAL):
// Block = 512 threads (8 waves) = 128 q of one (b,h).
//   waves 0-3 (group 0): keys   0..511; waves 4-7 (group 1): keys 512..1023
// Mask loaded at top of each kt (independent load). SPILL LEDGER — do NOT
// extend accumulator lifetimes: R2 mask-prefetch (+96MB WRITE), R13 forced
// occupancy (+600MB), R15 QK-hoist sm[2] (+27MB) all spill-regressed; this
// kernel sits at a 64-VGPR cliff.
// Pack via v_permlane32_swap_b32; s_setprio(1) around MFMA clusters (T5).
// Cross-group combine via one LDS exchange (exp2 softmax -> pure (o,l) add).
// XCD swizzle: co-(b,h) blocks share an XCD L2.
// ---------------------------------------------------------------------------
__global__ __launch_bounds__(512, 4) void attn_mfma(
    const ushort* __restrict__ Q, const ushort* __restrict__ K,
    const ushort* __restrict__ Vt, const uint* __restrict__ Mw,
    float* __restrict__ out)
{
    const int n  = blockIdx.x;                 // 0..511
    const int qt = (n >> 3) & 7;
    const int bh = (n & 7) | ((n >> 6) << 3);  // 0..63
    const int h  = bh & 15;
    const int b  = bh >> 4;

    const int tid  = threadIdx.x;
    const int w    = tid >> 6, lane = tid & 63;
    const int g    = w >> 2;                   // key-half group
    const int wq   = w & 3;                    // q-subtile within block
    const int col  = lane & 31, hi = lane >> 5;

    const size_t hb = ((size_t)(b * Hn + h)) * Sn * HDn;
    const ushort* Kg = K + hb;          // [key][dim]
    const ushort* Vg = Vt + hb;         // [dim][key]

    __shared__ __align__(16) ushort KV[2][2][2][64 * 72];

    short8 qf[4];
#pragma unroll
    for (int kp = 0; kp < 4; ++kp)
        qf[kp] = *(const short8*)&Q[hb +
            (size_t)(qt * 128 + wq * 32 + col) * HDn + kp * 16 + hi * 8];

    float16v o_[2];
#pragma unroll
    for (int dt = 0; dt < 2; ++dt)
#pragma unroll
        for (int r = 0; r < 16; ++r) o_[dt][r] = 0.f;
    float ls = 0.f;

    const int t  = tid & 255;
    const int c0 = t, c1 = t + 256;
    const int la0 = (c0 >> 3) * 72 + (c0 & 7) * 8;
    const int la1 = (c1 >> 3) * 72 + (c1 & 7) * 8;
    const int kb  = g * 8;                     // first key-tile of this group

    uint4 k0 = *(const uint4*)&Kg[(size_t)(kb * 64 + (c0 >> 3)) * HDn + (c0 & 7) * 8];
    uint4 k1 = *(const uint4*)&Kg[(size_t)(kb * 64 + (c1 >> 3)) * HDn + (c1 & 7) * 8];
    uint4 v0 = *(const uint4*)&Vg[(size_t)(c0 >> 3) * Sn + kb * 64 + (c0 & 7) * 8];
    uint4 v1 = *(const uint4*)&Vg[(size_t)(c1 >> 3) * Sn + kb * 64 + (c1 & 7) * 8];
    *(uint4*)&KV[g][0][0][la0] = k0;  *(uint4*)&KV[g][0][0][la1] = k1;
    *(uint4*)&KV[g][0][1][la0] = v0;  *(uint4*)&KV[g][0][1][la1] = v1;
    __syncthreads();

    const uint* mbase = Mw + ((size_t)((b * 8 + qt) * 16) * 4 + wq) * 1024 + lane * 16;

    for (int kt = 0; kt < 8; ++kt) {
        const int cur = kt & 1;
        if (kt < 7) {
            const int nk = (kb + kt + 1) * 64;
            k0 = *(const uint4*)&Kg[(size_t)(nk + (c0 >> 3)) * HDn + (c0 & 7) * 8];
            k1 = *(const uint4*)&Kg[(size_t)(nk + (c1 >> 3)) * HDn + (c1 & 7) * 8];
            v0 = *(const uint4*)&Vg[(size_t)(c0 >> 3) * Sn + nk + (c0 & 7) * 8];
            v1 = *(const uint4*)&Vg[(size_t)(c1 >> 3) * Sn + nk + (c1 & 7) * 8];
        }
        const uint* mp = mbase + (size_t)(kb + kt) * 4096;
        uint4 mk4[4];
        mk4[0] = *(const uint4*)(mp);
        mk4[1] = *(const uint4*)(mp + 4);
        mk4[2] = *(const uint4*)(mp + 8);
        mk4[3] = *(const uint4*)(mp + 12);
        const uint* mka = (const uint*)mk4;   // [mt*8 + pr]

#pragma unroll
        for (int mt = 0; mt < 2; ++mt) {
            float16v s_;
#pragma unroll
            for (int r = 0; r < 16; ++r) s_[r] = 0.f;
            __builtin_amdgcn_s_setprio(1);
#pragma unroll
            for (int kp = 0; kp < 4; ++kp) {
                short8 ak = *(const short8*)&KV[g][cur][0][(mt * 32 + col) * 72 + kp * 16 + hi * 8];
                s_ = __builtin_amdgcn_mfma_f32_32x32x16_bf16(ak, qf[kp], s_, 0, 0, 0);
            }
            __builtin_amdgcn_s_setprio(0);

            unsigned up[8];
#pragma unroll
            for (int pr = 0; pr < 8; ++pr) {
                const unsigned e0 = __float_as_uint(exp2f(s_[2 * pr]))     + 0x8000u;
                const unsigned e1 = __float_as_uint(exp2f(s_[2 * pr + 1])) + 0x8000u;
                const unsigned u  = __builtin_amdgcn_perm(e1, e0, 0x07060302u) & mka[mt * 8 + pr];
                up[pr] = u;
                ls += __uint_as_float(u << 16) + __uint_as_float(u & 0xffff0000u);
            }

            __builtin_amdgcn_s_setprio(1);
#pragma unroll
            for (int kh = 0; kh < 2; ++kh) {
                auto s02 = __builtin_amdgcn_permlane32_swap(
                    up[kh * 4 + 0], up[kh * 4 + 2], false, false);
                auto s13 = __builtin_amdgcn_permlane32_swap(
                    up[kh * 4 + 1], up[kh * 4 + 3], false, false);
                union { short8 s; unsigned u[4]; } f;
                f.u[0] = s02[0];
                f.u[1] = s13[0];
                f.u[2] = s02[1];
                f.u[3] = s13[1];
                const int kp = mt * 2 + kh;
#pragma unroll
                for (int dt = 0; dt < 2; ++dt) {
                    short8 av = *(const short8*)&KV[g][cur][1][(dt * 32 + col) * 72 + kp * 16 + hi * 8];
                    o_[dt] = __builtin_amdgcn_mfma_f32_32x32x16_bf16(av, f.s, o_[dt], 0, 0, 0);
                }
            }
            __builtin_amdgcn_s_setprio(0);
        }

        if (kt < 7) {
            const int nxt = cur ^ 1;
            *(uint4*)&KV[g][nxt][0][la0] = k0;  *(uint4*)&KV[g][nxt][0][la1] = k1;
            *(uint4*)&KV[g][nxt][1][la0] = v0;  *(uint4*)&KV[g][nxt][1][la1] = v1;
        }
        __syncthreads();
    }

    // ---- cross-group combine (reuse KV LDS; all tile reads done) ----
    float* xo  = (float*)&KV[0][0][0][0];         // 4 waves x 64 lanes x 36 f32
    float* lsx = xo + 4 * 64 * 36;                // + 256 f32  (38.9 KB total)
    if (g == 1) {
        float* dst = &xo[(wq * 64 + lane) * 36];
#pragma unroll
        for (int dt = 0; dt < 2; ++dt)
#pragma unroll
            for (int r4 = 0; r4 < 4; ++r4) {
                float4 o4 = make_float4(o_[dt][r4 * 4 + 0], o_[dt][r4 * 4 + 1],
                                        o_[dt][r4 * 4 + 2], o_[dt][r4 * 4 + 3]);
                *(float4*)&dst[dt * 16 + r4 * 4] = o4;
            }
        lsx[wq * 64 + lane] = ls;
    }
    __syncthreads();
    if (g == 0) {
        const float* src = &xo[(wq * 64 + lane) * 36];
        const float lt = ls + lsx[wq * 64 + lane];
        const float l  = lt + (float)__shfl_xor(lt, 32, 64);
        const float inv = 1.0f / l;
        const int q = qt * 128 + wq * 32 + col;
        float* op = &out[((size_t)b * Sn + q) * Dn + h * 64];
#pragma unroll
        for (int dt = 0; dt < 2; ++dt)
#pragma unroll
            for (int rg = 0; rg < 4; ++rg) {
                float4 s4 = *(const float4*)&src[dt * 16 + rg * 4];
                const int d = dt * 32 + rg * 8 + hi * 4;
                float4 o4;
                o4.x = fmaxf((o_[dt][rg * 4 + 0] + s4.x) * inv, 0.0f);
                o4.y = fmaxf((o_[dt][rg * 4 + 1] + s4.y) * inv, 0.0f);
                o4.z = fmaxf((o_[dt][rg * 4 + 2] + s4.z) * inv, 0.0f);
                o4.w = fmaxf((o_[dt][rg * 4 + 3] + s4.w) * inv, 0.0f);
                *(float4*)&op[d] = o4;
            }
    }
}

extern "C" void kernel_launch(void* const* d_in, const int* in_sizes, int n_in,
                              void* d_out, int out_size, void* d_ws, size_t ws_size,
                              hipStream_t stream)
{
    const float* x   = (const float*)d_in[0];
    const float* adj = (const float*)d_in[1];
    const float* Wq  = (const float*)d_in[2];
    const float* bq  = (const float*)d_in[3];
    const float* Wk  = (const float*)d_in[4];
    const float* bk  = (const float*)d_in[5];
    const float* Wv  = (const float*)d_in[6];
    const float* bv  = (const float*)d_in[7];
    float* out = (float*)d_out;

    // ws (ushort): xb[4.19M] | Wt[3.15M] | Qb | Kb | Vb [4.19M ea] then Mb (uint, 8.4 MB)
    ushort* xb = (ushort*)d_ws;
    ushort* Wt = xb + (size_t)Bn * Sn * Dn;
    ushort* Qb = Wt + (size_t)3 * Dn * Dn;
    ushort* Kb = Qb + (size_t)Bn * Hn * Sn * HDn;
    ushort* Vb = Kb + (size_t)Bn * Hn * Sn * HDn;
    uint*   Mb = (uint*)(Vb + (size_t)Bn * Hn * Sn * HDn);

    prep<<<dim3(2816), 256, 0, stream>>>(x, Wq, Wk, Wv, xb, Wt);

    qkv_gemm<<<dim3(1280), 256, 0, stream>>>(
        xb, Wt, bq, bk, bv, adj, Qb, Kb, Vb, Mb, out);

    attn_mfma<<<dim3(512), 512, 0, stream>>>(Qb, Kb, Vb, Mb, out);
}